// Round 11
// baseline (301.448 us; speedup 1.0000x reference)
//
#include <hip/hip_runtime.h>
#include <hip/hip_bf16.h>

typedef unsigned short u16;
typedef __bf16 bf16x8 __attribute__((ext_vector_type(8)));
typedef float f32x4 __attribute__((ext_vector_type(4)));

// Problem constants (B=4, S=2048, D=4096, E=8, r=8)
constexpr int Mdim = 8192;   // B*S
constexpr int Ndim = 4096;   // D (output features)
constexpr int Kdim = 4096;   // D (input features)
constexpr int ER   = 64;     // E*r
constexpr float LSCALE = 2.0f;  // alpha/r = 16/8

// round-to-nearest-even fp32 -> bf16 (finite inputs)
__device__ __forceinline__ u16 f2bf(float f) {
    union { float f; unsigned u; } v; v.f = f;
    unsigned r = v.u + 0x7fffu + ((v.u >> 16) & 1u);
    return (u16)(r >> 16);
}

#define GLOAD_LDS16(g, l)                                             \
    __builtin_amdgcn_global_load_lds(                                 \
        (const __attribute__((address_space(1))) void*)(g),           \
        (__attribute__((address_space(3))) void*)(l), 16, 0, 0)

// ---------------------------------------------------------------------------
// Kernel 1: W_eff[o,i] = W[o,i] + SCALE * sum_{er} Bcat[o,er]*Acat[er,i] (bf16)
// ---------------------------------------------------------------------------
__global__ __launch_bounds__(256) void weff_kernel(
    const float* __restrict__ W, const float* __restrict__ A,
    const float* __restrict__ Bm, u16* __restrict__ Wb)
{
    __shared__ __align__(16) float sAc[ER][128];
    __shared__ __align__(16) float sBc[64][ER];

    const int t  = threadIdx.x;
    const int i0 = blockIdx.x * 128;
    const int o0 = blockIdx.y * 64;

#pragma unroll
    for (int p = 0; p < 8; ++p) {
        int lin = p * 1024 + t * 4;
        int er = lin >> 7, ci = lin & 127;
        *(float4*)&sAc[er][ci] = *(const float4*)(A + (size_t)er * Kdim + i0 + ci);
    }
    {
        int ol = t >> 2;
        int c  = (t & 3) * 16;
#pragma unroll
        for (int q = 0; q < 2; ++q) {
            int er = c + q * 8;
            int e  = er >> 3;
            const float* src = Bm + ((size_t)e * Ndim + (o0 + ol)) * 8;
            *(float4*)&sBc[ol][er]     = *(const float4*)(src);
            *(float4*)&sBc[ol][er + 4] = *(const float4*)(src + 4);
        }
    }
    __syncthreads();

    const int tx = t & 31;
    const int ty = t >> 5;
    float acc[8][4] = {};
#pragma unroll 4
    for (int er = 0; er < ER; ++er) {
        float4 a = *(const float4*)&sAc[er][tx * 4];
#pragma unroll
        for (int q = 0; q < 8; ++q) {
            float bv = sBc[q * 8 + ty][er];
            acc[q][0] += bv * a.x;
            acc[q][1] += bv * a.y;
            acc[q][2] += bv * a.z;
            acc[q][3] += bv * a.w;
        }
    }
#pragma unroll
    for (int q = 0; q < 8; ++q) {
        int o = o0 + q * 8 + ty;
        const float4 w = *(const float4*)(W + (size_t)o * Kdim + i0 + tx * 4);
        ushort4 st;
        st.x = f2bf(w.x + LSCALE * acc[q][0]);
        st.y = f2bf(w.y + LSCALE * acc[q][1]);
        st.z = f2bf(w.z + LSCALE * acc[q][2]);
        st.w = f2bf(w.w + LSCALE * acc[q][3]);
        *(ushort4*)(Wb + (size_t)o * Kdim + i0 + tx * 4) = st;
    }
}

// ---------------------------------------------------------------------------
// Kernel 2: x fp32 -> bf16, 8 elements/thread
// ---------------------------------------------------------------------------
__global__ __launch_bounds__(256) void cvt_x_kernel(
    const float* __restrict__ x, u16* __restrict__ xb)
{
    size_t i = (size_t)blockIdx.x * blockDim.x + threadIdx.x;
    const float4 v0 = *(const float4*)(x + i * 8);
    const float4 v1 = *(const float4*)(x + i * 8 + 4);
    uint4 o;
    o.x = (unsigned)f2bf(v0.x) | ((unsigned)f2bf(v0.y) << 16);
    o.y = (unsigned)f2bf(v0.z) | ((unsigned)f2bf(v0.w) << 16);
    o.z = (unsigned)f2bf(v1.x) | ((unsigned)f2bf(v1.y) << 16);
    o.w = (unsigned)f2bf(v1.z) | ((unsigned)f2bf(v1.w) << 16);
    *(uint4*)(xb + i * 8) = o;
}

// ---------------------------------------------------------------------------
// Kernel 3: 256x256x32 GEMM, 8 waves (2Mx4N), FOUR LDS buffers, 2-tile-ahead
// staging with COUNTED vmcnt(4) (never 0 in the loop) and NO lgkm drain.
// Round-11 rationale: r6 (best, 4310 cyc/tile) loses ~1500 cyc/tile to the
// tile-top full drain (vmcnt(0)+lgkmcnt(0)). With 4 buffers (BK=32, 32 KB
// each) tile T+2's stages go to the buffer last read at T-2 -- two barriers
// separate write from last read, so no lgkm drain is needed, and vmcnt(4)
// leaves tile T+1's 4 loads in flight across the whole tile (m218's counted
// -vmcnt lever). All 12 ds_reads issue BEFORE the held MFMA cluster (bfr is
// parity-double-buffered P/Q so the held MQH's operands are never clobbered)
// -> every DS batch is covered by a 16-MFMA cluster.
// Per tile: 4 gloads/thread, 12 ds_read_b128/wave, 32 MFMA/wave (2 clusters).
// Swizzle: r8's BK=32 scheme, measured ZERO conflicts: stored chunk =
// global chunk ^ ((row>>1)&3) via pre-swizzled source; same XOR on reads.
// Race-freedom proof sketch (per-wave program order + barriers):
//  - buffer W written at tile T (stage T+2) was last ds_read at tile T-2;
//    those reads are register-drained before each wave's first MFMA after
//    T-1's barrier, hence before any wave reaches T's barrier. SAFE.
//  - tile T's data (staged at T-2) landed: each wave's own vmcnt(4) before
//    T's barrier covers its loads; barrier joins all waves. SAFE.
// ---------------------------------------------------------------------------
constexpr int BM = 256, BN = 256, BK = 32;
constexpr int NT = Kdim / BK;  // 128

__global__ __launch_bounds__(512, 2) void gemm_bias_kernel(
    const u16* __restrict__ Xb, const u16* __restrict__ Wb,
    const float* __restrict__ bias, float* __restrict__ C)
{
    __shared__ __align__(16) u16 lds[65536];   // 128 KiB = 4 bufs x 32 KB

    const int t    = threadIdx.x;
    const int lane = t & 63;
    const int wv   = t >> 6;
    const int wr   = wv >> 2;   // 0..1
    const int wc   = wv & 3;    // 0..3

    // XCD-aware swizzle: 512 blocks = 8 XCDs x 64; each XCD owns a 16x4 region
    const int wg  = blockIdx.x;
    const int xcd = wg & 7, lid = wg >> 3;
    const int mt  = (xcd & 1) * 16 + (lid >> 2);   // 0..31
    const int ntl = (xcd >> 1) * 4 + (lid & 3);    // 0..15
    const int bm  = mt * BM;
    const int bn  = ntl * BN;

    u16* bb0 = lds;              // buf k: A at [0,8192), B at [8192,16384) u16
    u16* bb1 = lds + 16384;
    u16* bb2 = lds + 32768;
    u16* bb3 = lds + 49152;

    // --- staging: 4 x global_load_lds(16B) per thread per K-tile ---
    // chunk c (0..1023): row = c>>2, col-chunk = c&3. LDS dest linear;
    // global source chunk = (c ^ (c>>3)) & 3 (= col ^ ((row>>1)&3), involution)
    const u16* gSrc[4]; int dOff[4];
#pragma unroll
    for (int i = 0; i < 4; ++i) {
        const int isB = i >> 1;
        const int c   = (i & 1) * 512 + t;                // 0..1023
        const int row = c >> 2;                           // 0..255
        const int scl = ((c ^ (c >> 3)) & 3) * 8;         // swizzled col (u16)
        gSrc[i] = (isB ? Wb + (size_t)(bn + row) * Kdim
                       : Xb + (size_t)(bm + row) * Kdim) + scl;
        dOff[i] = isB * 8192 + c * 8;
    }

    // --- fragment ds_read addressing (swizzled, 16-row span, 0 conflicts) ---
    const int fr = lane & 15;
    const int cp = (((lane >> 4) ^ (fr >> 1)) & 3) * 8;

    f32x4 acc[8][4];
#pragma unroll
    for (int i = 0; i < 8; ++i)
#pragma unroll
        for (int j = 0; j < 4; ++j)
            acc[i][j] = f32x4{0.f, 0.f, 0.f, 0.f};

    bf16x8 afA[4], afB[4];     // A m-half fragments (rows wr*128 +0..63/+64..127)
    bf16x8 bfrP[4], bfrQ[4];   // B fragments, parity double-buffered

#define DS_AFRAG(BUF, ARR, MH)                                                \
    _Pragma("unroll")                                                         \
    for (int mi = 0; mi < 4; ++mi)                                            \
        ARR[mi] = *(const bf16x8*)                                            \
            &(BUF)[(wr * 128 + (MH) * 64 + mi * 16 + fr) * 32 + cp];

#define DS_BFRAG(BUF, BARR)                                                   \
    _Pragma("unroll")                                                         \
    for (int ni = 0; ni < 4; ++ni)                                            \
        BARR[ni] = *(const bf16x8*)                                           \
            &(BUF)[8192 + (wc * 64 + ni * 16 + fr) * 32 + cp];

#define MQH(ARR, BARR, MH)                                                    \
    __builtin_amdgcn_s_setprio(1);                                            \
    _Pragma("unroll")                                                         \
    for (int mi = 0; mi < 4; ++mi)                                            \
        _Pragma("unroll")                                                     \
        for (int ni = 0; ni < 4; ++ni)                                        \
            acc[(MH)*4 + mi][ni] = __builtin_amdgcn_mfma_f32_16x16x32_bf16(   \
                ARR[mi], BARR[ni], acc[(MH)*4 + mi][ni], 0, 0, 0);            \
    __builtin_amdgcn_s_setprio(0);

#define FENCE asm volatile("" ::: "memory")
#define BAR   __builtin_amdgcn_s_barrier(); FENCE

    // TILE(T): vmcnt(VMS) BEFORE the barrier (per-wave landing guarantee,
    // joined by the barrier). Body: issue ALL 12 ds_reads of tile T (afA +
    // bfr[parity]); issue 4 gloads for tile T+2; MQH(afB of T-1 x bfr of
    // T-1 parity) -- held cluster covers the DS burst; MQH(afA x bfr);
    // DS afB (held to T+1). No lgkm drain anywhere -- compiler inserts
    // counted lgkm waits before each dependent MFMA cluster.
#define TILE(CUR, NXT, BC, BP, FIRST, DOSTAGE, VMS)                           \
    {                                                                         \
        asm volatile("s_waitcnt vmcnt(" VMS ")" ::: "memory");                \
        BAR;                                                                  \
        DS_AFRAG(CUR, afA, 0);                                                \
        DS_BFRAG(CUR, BC);                                                    \
        if (DOSTAGE) {                                                        \
            _Pragma("unroll")                                                 \
            for (int i = 0; i < 4; ++i)                                       \
                GLOAD_LDS16(gSrc[i] + koff, (NXT) + dOff[i]);                 \
            koff += 32;                                                       \
        }                                                                     \
        if (!(FIRST)) { MQH(afB, BP, 1); }                                    \
        MQH(afA, BC, 0);                                                      \
        DS_AFRAG(CUR, afB, 1);                                                \
    }

    // prologue: stage tile 0 -> bb0, tile 1 -> bb1
#pragma unroll
    for (int i = 0; i < 4; ++i) GLOAD_LDS16(gSrc[i], bb0 + dOff[i]);
#pragma unroll
    for (int i = 0; i < 4; ++i) GLOAD_LDS16(gSrc[i] + 32, bb1 + dOff[i]);

    int koff = 64;   // k element-offset of the next tile to stage (tile 2)

    TILE(bb0, bb2, bfrP, bfrQ, 1, 1, "4");   // T0   (stages T2)
    TILE(bb1, bb3, bfrQ, bfrP, 0, 1, "4");   // T1   (stages T3)
#pragma unroll 1
    for (int g = 0; g < (NT - 4) / 4; ++g) { // T2..T125 (31 groups of 4)
        TILE(bb2, bb0, bfrP, bfrQ, 0, 1, "4");
        TILE(bb3, bb1, bfrQ, bfrP, 0, 1, "4");
        TILE(bb0, bb2, bfrP, bfrQ, 0, 1, "4");
        TILE(bb1, bb3, bfrQ, bfrP, 0, 1, "4");
    }
    TILE(bb2, bb0, bfrP, bfrQ, 0, 0, "4");   // T126 (no stage)
    TILE(bb3, bb1, bfrQ, bfrP, 0, 0, "0");   // T127 (no stage, full drain)
    MQH(afB, bfrQ, 1);                       // drain held mh1 of T127

#undef TILE
#undef MQH
#undef DS_BFRAG
#undef DS_AFRAG

    // epilogue: bias add + store (C/D layout: col=lane&15, row=(lane>>4)*4+j)
#pragma unroll
    for (int ni = 0; ni < 4; ++ni) {
        const int col = bn + wc * 64 + ni * 16 + (lane & 15);
        const float bv = bias[col];
#pragma unroll
        for (int mi = 0; mi < 8; ++mi) {
            const int rbase = bm + wr * 128 + mi * 16 + (lane >> 4) * 4;
#pragma unroll
            for (int j = 0; j < 4; ++j)
                C[(size_t)(rbase + j) * Ndim + col] = acc[mi][ni][j] + bv;
        }
    }
}

// ---------------------------------------------------------------------------
// Fallback (only if ws too small): slow but correct fp32 row-per-block kernel
// ---------------------------------------------------------------------------
__global__ __launch_bounds__(256) void naive_row_kernel(
    const float* __restrict__ x, const float* __restrict__ W,
    const float* __restrict__ bias, const float* __restrict__ A,
    const float* __restrict__ Bm, float* __restrict__ out)
{
    __shared__ float sx[Kdim];
    __shared__ float st[ER];
    const int m = blockIdx.x;
    const float* xr = x + (size_t)m * Kdim;
    for (int i = threadIdx.x; i < Kdim; i += 256) sx[i] = xr[i];
    __syncthreads();
    if (threadIdx.x < ER) {
        const float* ar = A + (size_t)threadIdx.x * Kdim;
        float s = 0.f;
        for (int i = 0; i < Kdim; ++i) s += sx[i] * ar[i];
        st[threadIdx.x] = s;
    }
    __syncthreads();
    for (int o = threadIdx.x; o < Ndim; o += 256) {
        const float* wr = W + (size_t)o * Kdim;
        float s = bias[o];
        for (int i = 0; i < Kdim; ++i) s += sx[i] * wr[i];
        float l = 0.f;
        for (int e = 0; e < 8; ++e) {
            const float* bp = Bm + ((size_t)e * Ndim + o) * 8;
            for (int r = 0; r < 8; ++r) l += st[e * 8 + r] * bp[r];
        }
        out[(size_t)m * Ndim + o] = s + LSCALE * l;
    }
}

extern "C" void kernel_launch(void* const* d_in, const int* in_sizes, int n_in,
                              void* d_out, int out_size, void* d_ws, size_t ws_size,
                              hipStream_t stream)
{
    const float* x  = (const float*)d_in[0];
    const float* W  = (const float*)d_in[1];
    const float* b  = (const float*)d_in[2];
    const float* A  = (const float*)d_in[3];
    const float* Bm = (const float*)d_in[4];
    float* out = (float*)d_out;

    const size_t xb_bytes = (size_t)Mdim * Kdim * 2;   // 64 MB
    const size_t wb_bytes = (size_t)Ndim * Kdim * 2;   // 32 MB

    if (ws_size >= xb_bytes + wb_bytes) {
        u16* Xb = (u16*)d_ws;
        u16* Wb = (u16*)((char*)d_ws + xb_bytes);
        cvt_x_kernel<<<(Mdim * (size_t)Kdim) / 8 / 256, 256, 0, stream>>>(x, Xb);
        weff_kernel<<<dim3(Kdim / 128, Ndim / 64), 256, 0, stream>>>(W, A, Bm, Wb);
        gemm_bias_kernel<<<dim3((Mdim / BM) * (Ndim / BN)), 512, 0, stream>>>(Xb, Wb, b, out);
    } else {
        naive_row_kernel<<<Mdim, 256, 0, stream>>>(x, W, b, A, Bm, out);
    }
}

// Round 12
// 290.648 us; speedup vs baseline: 1.0372x; 1.0372x over previous
//
#include <hip/hip_runtime.h>
#include <hip/hip_bf16.h>

typedef unsigned short u16;
typedef __bf16 bf16x8 __attribute__((ext_vector_type(8)));
typedef float f32x4 __attribute__((ext_vector_type(4)));

// Problem constants (B=4, S=2048, D=4096, E=8, r=8)
constexpr int Mdim = 8192;   // B*S
constexpr int Ndim = 4096;   // D (output features)
constexpr int Kdim = 4096;   // D (input features)
constexpr int ER   = 64;     // E*r
constexpr float LSCALE = 2.0f;  // alpha/r = 16/8

// round-to-nearest-even fp32 -> bf16 (finite inputs)
__device__ __forceinline__ u16 f2bf(float f) {
    union { float f; unsigned u; } v; v.f = f;
    unsigned r = v.u + 0x7fffu + ((v.u >> 16) & 1u);
    return (u16)(r >> 16);
}

#define GLOAD_LDS16(g, l)                                             \
    __builtin_amdgcn_global_load_lds(                                 \
        (const __attribute__((address_space(1))) void*)(g),           \
        (__attribute__((address_space(3))) void*)(l), 16, 0, 0)

// ---------------------------------------------------------------------------
// Fused pre-pass: cvt_x (16384 logical blocks) + weff (2048 logical blocks),
// interleaved 8:1 so both run concurrently (bx%9==8 -> weff).
//   cvt: Xb[i] = bf16(x[i]), 8 elems/thread.
//   weff: Wb[o,i] = bf16(W[o,i] + SCALE * sum_er Bcat[o,er]*Acat[er,i]).
// ---------------------------------------------------------------------------
__global__ __launch_bounds__(256) void fused_pre_kernel(
    const float* __restrict__ x, const float* __restrict__ W,
    const float* __restrict__ A, const float* __restrict__ Bm,
    u16* __restrict__ Xb, u16* __restrict__ Wb)
{
    __shared__ __align__(16) float sAc[ER][128];
    __shared__ __align__(16) float sBc[64][ER];

    const int bx = blockIdx.x;
    const int t  = threadIdx.x;

    if ((bx % 9) != 8) {
        // ---- cvt_x part ----
        const int ci = (bx / 9) * 8 + (bx % 9);      // 0..16383
        const size_t i = ((size_t)ci * 256 + t) * 8;
        const float4 v0 = *(const float4*)(x + i);
        const float4 v1 = *(const float4*)(x + i + 4);
        uint4 o;
        o.x = (unsigned)f2bf(v0.x) | ((unsigned)f2bf(v0.y) << 16);
        o.y = (unsigned)f2bf(v0.z) | ((unsigned)f2bf(v0.w) << 16);
        o.z = (unsigned)f2bf(v1.x) | ((unsigned)f2bf(v1.y) << 16);
        o.w = (unsigned)f2bf(v1.z) | ((unsigned)f2bf(v1.w) << 16);
        *(uint4*)(Xb + i) = o;
        return;
    }

    // ---- weff part ----
    const int w  = bx / 9;                           // 0..2047
    const int i0 = (w & 31) * 128;
    const int o0 = (w >> 5) * 64;

#pragma unroll
    for (int p = 0; p < 8; ++p) {
        int lin = p * 1024 + t * 4;
        int er = lin >> 7, ci2 = lin & 127;
        *(float4*)&sAc[er][ci2] = *(const float4*)(A + (size_t)er * Kdim + i0 + ci2);
    }
    {
        int ol = t >> 2;
        int c  = (t & 3) * 16;
#pragma unroll
        for (int q = 0; q < 2; ++q) {
            int er = c + q * 8;
            int e  = er >> 3;
            const float* src = Bm + ((size_t)e * Ndim + (o0 + ol)) * 8;
            *(float4*)&sBc[ol][er]     = *(const float4*)(src);
            *(float4*)&sBc[ol][er + 4] = *(const float4*)(src + 4);
        }
    }
    __syncthreads();

    const int tx = t & 31;
    const int ty = t >> 5;
    float acc[8][4] = {};
#pragma unroll 4
    for (int er = 0; er < ER; ++er) {
        float4 a = *(const float4*)&sAc[er][tx * 4];
#pragma unroll
        for (int q = 0; q < 8; ++q) {
            float bv = sBc[q * 8 + ty][er];
            acc[q][0] += bv * a.x;
            acc[q][1] += bv * a.y;
            acc[q][2] += bv * a.z;
            acc[q][3] += bv * a.w;
        }
    }
#pragma unroll
    for (int q = 0; q < 8; ++q) {
        int o = o0 + q * 8 + ty;
        const float4 wv4 = *(const float4*)(W + (size_t)o * Kdim + i0 + tx * 4);
        ushort4 st;
        st.x = f2bf(wv4.x + LSCALE * acc[q][0]);
        st.y = f2bf(wv4.y + LSCALE * acc[q][1]);
        st.z = f2bf(wv4.z + LSCALE * acc[q][2]);
        st.w = f2bf(wv4.w + LSCALE * acc[q][3]);
        *(ushort4*)(Wb + (size_t)o * Kdim + i0 + tx * 4) = st;
    }
}

// ---------------------------------------------------------------------------
// GEMM: 256x256x64, m201-template 8-phase schedule (2 K-tiles per iter).
// 512 threads = 8 waves (2M x 4N); per-wave out 128x64 = acc[8][4] f32x4.
// LDS 128 KiB = 2 tile-bufs x 4 half-slots (A0,A1,B0,B1; 128x64 bf16 each).
// Per phase: {ds-subtile; stage 1 half-tile (2 gloads); [waits]; BAR;
//             lgkmcnt(0); setprio(1); 16 MFMA; setprio(0); BAR}.
// vmcnt(6) ONLY at P4 and P8 (3 half-tiles in flight; never 0 in loop).
// Stage order (iter = tiles E,O): P1:O:A1->buf1, P2:E+2:B0, P3:E+2:B1,
// P4:E+2:A0 +vmcnt6, P5:E+2:A1, P6:O+2:B0, P7:O+2:B1, P8:O+2:A0 +vmcnt6.
// Verified invariants: every slot staged >=1 barrier-pair after its last
// ds_read (reads drained by each phase's lgkmcnt(0) before its BAR2);
// vmcnt(6)@P4 lands O's 4 halves before P5; @P8 lands E+2's before next P1.
// Tail: stage offsets wrap (&63) -- same slot discipline, bookkeeping uniform.
// Swizzle (r4-r6, measured 0 conflicts): stored chunk = global chunk^(row&7)
// via pre-swizzled source col; reads XOR the same key.
// ---------------------------------------------------------------------------
constexpr int BM = 256, BN = 256, BK = 64;

__global__ __launch_bounds__(512, 2) void gemm_bias_kernel(
    const u16* __restrict__ Xb, const u16* __restrict__ Wb,
    const float* __restrict__ bias, float* __restrict__ C)
{
    __shared__ __align__(16) u16 lds[65536];   // 128 KiB

    const int t    = threadIdx.x;
    const int lane = t & 63;
    const int wv   = t >> 6;
    const int wr   = wv >> 2;   // 0..1
    const int wc   = wv & 3;    // 0..3

    // XCD-aware swizzle: 512 blocks = 8 XCDs x 64; each XCD owns a 16x4 region
    const int wg  = blockIdx.x;
    const int xcd = wg & 7, lid = wg >> 3;
    const int mt  = (xcd & 1) * 16 + (lid >> 2);   // 0..31
    const int ntl = (xcd >> 1) * 4 + (lid & 3);    // 0..15
    const int bm  = mt * BM;
    const int bn  = ntl * BN;

    u16* buf0 = lds;            // slots (u16): A0 +0, A1 +8192, B0 +16384, B1 +24576
    u16* buf1 = lds + 32768;

    // --- staging addresses: one half-tile = 128 rows x 64 cols = 2 gloads/thread
    const int rl  = t >> 3;                          // 0..63 row low
    const int scl = ((t ^ (t >> 3)) & 7) * 8;        // pre-swizzled col (u16)
    const u16* aSrc0 = Xb + (size_t)(bm + rl) * Kdim + scl;        // A-half0
    const u16* aSrc1 = Xb + (size_t)(bm + 128 + rl) * Kdim + scl;  // A-half1
    const u16* bSrc0 = Wb + (size_t)(bn + rl) * Kdim + scl;        // B-half0
    const u16* bSrc1 = Wb + (size_t)(bn + 128 + rl) * Kdim + scl;  // B-half1
    constexpr size_t R64 = (size_t)64 * Kdim;        // +64 rows

#define STG(BUF, SLOT, SRCP, KO)                                              \
    do {                                                                      \
        GLOAD_LDS16((SRCP) + (KO), (BUF) + (SLOT) + t * 8);                   \
        GLOAD_LDS16((SRCP) + (KO) + R64, (BUF) + (SLOT) + 4096 + t * 8);      \
    } while (0)

    // --- fragment ds_read addressing (swizzled, 16-row span) ---
    const int fr  = lane & 15;
    const int cp0 = (((lane >> 4) ^ (lane & 7)) & 7) * 8;          // kk=0
    const int cp1 = ((((lane >> 4) + 4) ^ (lane & 7)) & 7) * 8;    // kk=1
    const int aB  = wr * 8192;                                      // A-half slot
    const int bB  = 16384 + (wc >> 1) * 8192 + (wc & 1) * 4096;     // B row base

    f32x4 acc[8][4];
#pragma unroll
    for (int i = 0; i < 8; ++i)
#pragma unroll
        for (int j = 0; j < 4; ++j)
            acc[i][j] = f32x4{0.f, 0.f, 0.f, 0.f};

    bf16x8 af[4][2];      // A frags of current m-half (overwritten P3/P7)
    bf16x8 bf0[2][2];     // B frags nh0 (live P1..P4 / P5..P8)
    bf16x8 bf1[2][2];     // B frags nh1

#define DS_A(BUF, MH)                                                         \
    _Pragma("unroll")                                                         \
    for (int mi = 0; mi < 4; ++mi) {                                          \
        const int rb = aB + ((MH) * 64 + mi * 16 + fr) * 64;                  \
        af[mi][0] = *(const bf16x8*)&(BUF)[rb + cp0];                         \
        af[mi][1] = *(const bf16x8*)&(BUF)[rb + cp1];                         \
    }

#define DS_B(BUF, NH, BF)                                                     \
    _Pragma("unroll")                                                         \
    for (int ni = 0; ni < 2; ++ni) {                                          \
        const int rb = bB + ((NH) * 32 + ni * 16 + fr) * 64;                  \
        BF[ni][0] = *(const bf16x8*)&(BUF)[rb + cp0];                         \
        BF[ni][1] = *(const bf16x8*)&(BUF)[rb + cp1];                         \
    }

#define MQ(MH, NH, BF)                                                        \
    __builtin_amdgcn_s_setprio(1);                                            \
    _Pragma("unroll")                                                         \
    for (int mi = 0; mi < 4; ++mi)                                            \
        _Pragma("unroll")                                                     \
        for (int ni = 0; ni < 2; ++ni) {                                      \
            acc[(MH)*4 + mi][(NH)*2 + ni] =                                   \
                __builtin_amdgcn_mfma_f32_16x16x32_bf16(                      \
                    af[mi][0], BF[ni][0], acc[(MH)*4 + mi][(NH)*2 + ni],      \
                    0, 0, 0);                                                 \
            acc[(MH)*4 + mi][(NH)*2 + ni] =                                   \
                __builtin_amdgcn_mfma_f32_16x16x32_bf16(                      \
                    af[mi][1], BF[ni][1], acc[(MH)*4 + mi][(NH)*2 + ni],      \
                    0, 0, 0);                                                 \
        }                                                                     \
    __builtin_amdgcn_s_setprio(0);

#define FENCE asm volatile("" ::: "memory")
#define BAR   __builtin_amdgcn_s_barrier(); FENCE
#define LGKM0 asm volatile("s_waitcnt lgkmcnt(0)" ::: "memory");              \
              __builtin_amdgcn_sched_barrier(0)
#define VM6   asm volatile("s_waitcnt vmcnt(6)" ::: "memory")
#define LGK8  asm volatile("s_waitcnt lgkmcnt(8)" ::: "memory")

    // prologue: stage E0 {B0,B1,A0,A1} + O1 {B0,B1,A0}; land E0; sync.
    STG(buf0, 16384, bSrc0, 0);
    STG(buf0, 24576, bSrc1, 0);
    STG(buf0, 0,     aSrc0, 0);
    STG(buf0, 8192,  aSrc1, 0);
    STG(buf1, 16384, bSrc0, 64);
    STG(buf1, 24576, bSrc1, 64);
    STG(buf1, 0,     aSrc0, 64);
    VM6;   // allow newest 3 stages (O1) -> E0 fully landed
    BAR;

#pragma unroll 1
    for (int g = 0; g < 32; ++g) {
        const int koO  = (2 * g + 1) * 64;
        const int koE2 = ((2 * g + 2) & 63) * 64;
        const int koO2 = ((2 * g + 3) & 63) * 64;

        // P1: Q(0,0) of E
        DS_A(buf0, 0); DS_B(buf0, 0, bf0);
        STG(buf1, 8192, aSrc1, koO);          // O:A1
        LGK8;
        BAR; LGKM0; MQ(0, 0, bf0); BAR;
        // P2: Q(0,1) of E
        DS_B(buf0, 1, bf1);
        STG(buf0, 16384, bSrc0, koE2);        // E+2:B0
        BAR; LGKM0; MQ(0, 1, bf1); BAR;
        // P3: Q(1,1) of E
        DS_A(buf0, 1);
        STG(buf0, 24576, bSrc1, koE2);        // E+2:B1
        BAR; LGKM0; MQ(1, 1, bf1); BAR;
        // P4: Q(1,0) of E (register-held operands)
        STG(buf0, 0, aSrc0, koE2);            // E+2:A0
        VM6;                                   // O fully landed for P5
        BAR; MQ(1, 0, bf0); BAR;
        // P5: Q(0,0) of O
        DS_A(buf1, 0); DS_B(buf1, 0, bf0);
        STG(buf0, 8192, aSrc1, koE2);         // E+2:A1
        LGK8;
        BAR; LGKM0; MQ(0, 0, bf0); BAR;
        // P6: Q(0,1) of O
        DS_B(buf1, 1, bf1);
        STG(buf1, 16384, bSrc0, koO2);        // O+2:B0
        BAR; LGKM0; MQ(0, 1, bf1); BAR;
        // P7: Q(1,1) of O
        DS_A(buf1, 1);
        STG(buf1, 24576, bSrc1, koO2);        // O+2:B1
        BAR; LGKM0; MQ(1, 1, bf1); BAR;
        // P8: Q(1,0) of O
        STG(buf1, 0, aSrc0, koO2);            // O+2:A0
        VM6;                                   // E+2 fully landed for next P1
        BAR; MQ(1, 0, bf0); BAR;
    }

#undef STG
#undef DS_A
#undef DS_B
#undef MQ

    // epilogue: bias add + store (C/D layout: col=lane&15, row=(lane>>4)*4+j)
#pragma unroll
    for (int ni = 0; ni < 4; ++ni) {
        const int col = bn + wc * 64 + ni * 16 + (lane & 15);
        const float bv = bias[col];
#pragma unroll
        for (int mi = 0; mi < 8; ++mi) {
            const int rbase = bm + wr * 128 + mi * 16 + (lane >> 4) * 4;
#pragma unroll
            for (int j = 0; j < 4; ++j)
                C[(size_t)(rbase + j) * Ndim + col] = acc[mi][ni][j] + bv;
        }
    }
}

// ---------------------------------------------------------------------------
// Fallback (only if ws too small): slow but correct fp32 row-per-block kernel
// ---------------------------------------------------------------------------
__global__ __launch_bounds__(256) void naive_row_kernel(
    const float* __restrict__ x, const float* __restrict__ W,
    const float* __restrict__ bias, const float* __restrict__ A,
    const float* __restrict__ Bm, float* __restrict__ out)
{
    __shared__ float sx[Kdim];
    __shared__ float st[ER];
    const int m = blockIdx.x;
    const float* xr = x + (size_t)m * Kdim;
    for (int i = threadIdx.x; i < Kdim; i += 256) sx[i] = xr[i];
    __syncthreads();
    if (threadIdx.x < ER) {
        const float* ar = A + (size_t)threadIdx.x * Kdim;
        float s = 0.f;
        for (int i = 0; i < Kdim; ++i) s += sx[i] * ar[i];
        st[threadIdx.x] = s;
    }
    __syncthreads();
    for (int o = threadIdx.x; o < Ndim; o += 256) {
        const float* wr = W + (size_t)o * Kdim;
        float s = bias[o];
        for (int i = 0; i < Kdim; ++i) s += sx[i] * wr[i];
        float l = 0.f;
        for (int e = 0; e < 8; ++e) {
            const float* bp = Bm + ((size_t)e * Ndim + o) * 8;
            for (int r = 0; r < 8; ++r) l += st[e * 8 + r] * bp[r];
        }
        out[(size_t)m * Ndim + o] = s + LSCALE * l;
    }
}

extern "C" void kernel_launch(void* const* d_in, const int* in_sizes, int n_in,
                              void* d_out, int out_size, void* d_ws, size_t ws_size,
                              hipStream_t stream)
{
    const float* x  = (const float*)d_in[0];
    const float* W  = (const float*)d_in[1];
    const float* b  = (const float*)d_in[2];
    const float* A  = (const float*)d_in[3];
    const float* Bm = (const float*)d_in[4];
    float* out = (float*)d_out;

    const size_t xb_bytes = (size_t)Mdim * Kdim * 2;   // 64 MB
    const size_t wb_bytes = (size_t)Ndim * Kdim * 2;   // 32 MB

    if (ws_size >= xb_bytes + wb_bytes) {
        u16* Xb = (u16*)d_ws;
        u16* Wb = (u16*)((char*)d_ws + xb_bytes);
        fused_pre_kernel<<<18432, 256, 0, stream>>>(x, W, A, Bm, Xb, Wb);
        gemm_bias_kernel<<<dim3((Mdim / BM) * (Ndim / BN)), 512, 0, stream>>>(Xb, Wb, b, out);
    } else {
        naive_row_kernel<<<Mdim, 256, 0, stream>>>(x, W, b, A, Bm, out);
    }
}